// Round 10
// baseline (93.444 us; speedup 1.0000x reference)
//
#include <hip/hip_runtime.h>

// ---------------------------------------------------------------------------
// MalConvLowMem as GEMM: M=15748 windows (4096 contiguous floats), N=256
// (w1|w2), K=4096; epilogue g=(c1+b1)*sigmoid(c2+b2), max over positions.
// R10 = R9 + 32x32x16 MFMA: wave tile 32 rows x 32 cols (2 row-groups x
// 8 col-groups = 16 waves). Halves LDS A-read traffic (128->64 KB/step/CU)
// and MFMA issue. A in LDS ring-4 (8KB/slot), per-step lgkmcnt(0)+s_barrier.
// B in regs, fragment-major for 32x32 with gate-pair col permutation:
// col-group g covers {g*16..g*16+15} u {128+g*16..}; c1/c2 = lanes l, l^16.
// Epilogue in registers: shfl_xor(16) pair + shfl_xor(32) row reduce.
// ---------------------------------------------------------------------------

#define T_LEN 2000000
#define P_CNT 3937
#define M_TOT 15748
#define KD    4096

typedef __attribute__((ext_vector_type(8))) short short8;
typedef __attribute__((ext_vector_type(16))) float f32x16;

static __device__ __forceinline__ unsigned short f2bf(float f) {
    unsigned u = __builtin_bit_cast(unsigned, f);
    unsigned r = (u + 0x7FFFu + ((u >> 16) & 1u)) >> 16;   // RNE
    return (unsigned short)r;
}

static __device__ __forceinline__ unsigned ordenc(float f) {
    unsigned u = __builtin_bit_cast(unsigned, f);
    return (u & 0x80000000u) ? ~u : (u | 0x80000000u);
}

// (batch bb, position p<=3936) -> flat float offset of window start in x
static __device__ __forceinline__ size_t row_base_bp(int bb, int p) {
    int j, kp;
    if (p < 3875) { j = p / 125; kp = p - j * 125; }
    else          { j = 31;      kp = p - 3875; }
    long pos = (long)j * 63489 + (long)kp * 512;
    return ((size_t)bb * T_LEN + (size_t)pos) * 8u;
}

// 4 fp32 -> 4 bf16 (uint2) via v_cvt_pk_bf16_f32 (RNE)
static __device__ __forceinline__ uint2 cvt4(float4 v) {
    unsigned lo, hi;
    asm("v_cvt_pk_bf16_f32 %0, %1, %2" : "=v"(lo) : "v"(v.x), "v"(v.y));
    asm("v_cvt_pk_bf16_f32 %0, %1, %2" : "=v"(hi) : "v"(v.z), "v"(v.w));
    uint2 u; u.x = lo; u.y = hi;
    return u;
}

// ---------------------------------------------------------------------------
// Kernel 1: repack weights fragment-major for mfma_32x32x16 with gate-pair
// col permutation. uint4 chunk c = ((ks*4+s)*8+g)*64 + l holds, for
// cl=l&31, half=l>>5:
//   n = cl<16 ? g*16+cl : 128+g*16+(cl-16)
//   k = ks*64 + s*16 + half*8 + 0..7
//   W'[n][k] = (n<128?w1:w2)[n&127][e=k&7][t=k>>3] as bf16.
// Also init 512 output slots to order-encoded -inf.
// ---------------------------------------------------------------------------
__global__ __launch_bounds__(256) void pack_w(const float* __restrict__ w1,
                                              const float* __restrict__ w2,
                                              uint4* __restrict__ Bpf,
                                              unsigned* __restrict__ outu) {
    int c = blockIdx.x * 256 + threadIdx.x;         // grid 512 -> 131072
    if (c < 512) outu[c] = 0u;
    if (c >= 131072) return;
    int l    = c & 63;
    int g    = (c >> 6) & 7;
    int s    = (c >> 9) & 3;
    int ks   = c >> 11;
    int cl   = l & 31;
    int half = l >> 5;
    int n  = (cl < 16) ? (g * 16 + cl) : (128 + g * 16 + (cl - 16));
    int kb = ks * 64 + s * 16 + half * 8;
    const float* src = (n < 128) ? w1 : w2;
    int cc = n & 127;
    unsigned short h[8];
#pragma unroll
    for (int j = 0; j < 8; ++j) {
        int k = kb + j;
        h[j] = f2bf(src[cc * 4096 + (k & 7) * 512 + (k >> 3)]);
    }
    uint4 v;
    v.x = (unsigned)h[0] | ((unsigned)h[1] << 16);
    v.y = (unsigned)h[2] | ((unsigned)h[3] << 16);
    v.z = (unsigned)h[4] | ((unsigned)h[5] << 16);
    v.w = (unsigned)h[6] | ((unsigned)h[7] << 16);
    Bpf[c] = v;
}

// ---------------------------------------------------------------------------
// Kernel 2: GEMM + gate + max. 1024 thr / 16 waves; wave (mg=w>>3, g=w&7)
// owns rows mg*32..+31, virtual cols of group g. acc = one f32x16.
// ---------------------------------------------------------------------------
#define LOAD_B(BB, KS)                                                         \
    do {                                                                       \
        _Pragma("unroll")                                                      \
        for (int s = 0; s < 4; ++s)                                            \
            BB[s] = Bq[((KS) * 4 + s) * 512 + bbase];                          \
    } while (0)

#define STEP(KS, BCUR, BNXT)                                                   \
    do {                                                                       \
        const int ks_ = (KS);                                                  \
        const int ksn = (ks_ + 1 < 64) ? ks_ + 1 : 63;                         \
        LOAD_B(BNXT, ksn);                                                     \
        const int ksl = (ks_ + 4 < 64) ? ks_ + 4 : 63;                         \
        float4 aF = *(const float4*)(x + aoff + (size_t)(ksl * 64));           \
        const char* As = smem + (ks_ & 3) * 8192;                              \
        _Pragma("unroll")                                                      \
        for (int s = 0; s < 4; ++s) {                                          \
            short8 af = *(const short8*)(As + aro[s]);                         \
            short8 b  = __builtin_bit_cast(short8, BCUR[s]);                   \
            acc = __builtin_amdgcn_mfma_f32_32x32x16_bf16(af, b, acc, 0, 0, 0);\
        }                                                                      \
        *(uint2*)(smem + ((ks_ + 2) & 3) * 8192 + awb) = cvt4(aA);             \
        aA = aB; aB = aF;                                                      \
        asm volatile("s_waitcnt lgkmcnt(0)" ::: "memory");                     \
        __builtin_amdgcn_s_barrier();                                          \
        asm volatile("" ::: "memory");                                         \
    } while (0)

__global__ __launch_bounds__(1024, 4) void gemm_max(const float* __restrict__ x,
                                                    const uint4* __restrict__ Bq,
                                                    const float* __restrict__ b1,
                                                    const float* __restrict__ b2,
                                                    unsigned* __restrict__ outu) {
    __shared__ __align__(16) char smem[32768];      // ring-4 of 8KB

    const int t    = threadIdx.x;
    const int lane = t & 63;
    const int w    = t >> 6;                        // wave 0..15
    const int g    = w & 7;                         // col-group
    const int mg   = w >> 3;                        // row-group
    const int bid  = blockIdx.x;
    const int bb   = bid / 62;                      // batch (block-uniform)
    const int p0   = (bid % 62) * 64;               // first position of block

    // ---- A staging: thread t handles row=t>>4 (0..63), k-chunk t&15 ----
    const int rowS = t >> 4;
    const int kcS  = t & 15;
    int pS = p0 + rowS; if (pS > P_CNT - 1) pS = P_CNT - 1;
    const size_t aoff = row_base_bp(bb, pS) + (size_t)(kcS * 4);
    const int    awb  = (rowS * 128 + kcS * 8) ^ ((rowS & 7) << 4);

    // ---- A fragment read offsets [s] (XOR-swizzled): row=mg*32+(lane&31),
    // k-bytes = s*32 + (lane>>5)*16 ----
    int aro[4];
    {
        int row = mg * 32 + (lane & 31);
#pragma unroll
        for (int s = 0; s < 4; ++s)
            aro[s] = (row * 128 + s * 32 + (lane >> 5) * 16) ^ ((row & 7) << 4);
    }

    const int bbase = g * 64 + lane;                // uint4 units

    // ---- prologue: stage tiles 0,1; prime pipelines ----
#pragma unroll
    for (int pt = 0; pt < 2; ++pt) {
        float4 v = *(const float4*)(x + aoff + pt * 64);
        *(uint2*)(smem + pt * 8192 + awb) = cvt4(v);
    }
    __syncthreads();

    float4 aA = *(const float4*)(x + aoff + 128);   // tile 2
    float4 aB = *(const float4*)(x + aoff + 192);   // tile 3
    uint4 BX[4], BY[4];
    LOAD_B(BX, 0);

    f32x16 acc;
#pragma unroll
    for (int i = 0; i < 16; ++i) acc[i] = 0.f;

    for (int ks = 0; ks < 64; ks += 2) {
        STEP(ks, BX, BY);
        STEP(ks + 1, BY, BX);
    }

    // ---- epilogue: in-register gate + max ----
    // cl=lane&31: virtual col; physical c = g*16 + (cl&15); c1 in lanes
    // cl<16, c2 in lanes cl>=16 (same C/D rows: row=(r&3)+8*(r>>2)+4*(l>>5)).
    const int   cl   = lane & 31;
    const int   cidx = g * 16 + (cl & 15);
    const float bb1  = b1[cidx];
    const float bb2  = b2[cidx];
    float best = -3.4e38f;
#pragma unroll
    for (int r = 0; r < 16; ++r) {
        float v  = acc[r];
        float ov = __shfl_xor(v, 16);
        float a1 = (cl < 16) ? v : ov;
        float a2 = (cl < 16) ? ov : v;
        float gte = (a1 + bb1) / (1.f + __expf(-(a2 + bb2)));
        best = fmaxf(best, gte);
    }
    // cover the other 16 rows of this 32-row group (lane bit 5)
    best = fmaxf(best, __shfl_xor(best, 32));
    if (lane < 16)
        atomicMax(&outu[bb * 128 + g * 16 + lane], ordenc(best));
}

// ---------------------------------------------------------------------------
// Kernel 3: decode order-encoded uints to floats in place.
// ---------------------------------------------------------------------------
__global__ __launch_bounds__(256) void unmap_out(unsigned* __restrict__ outu) {
    int i = blockIdx.x * 256 + threadIdx.x;
    if (i < 512) {
        unsigned u = outu[i];
        outu[i] = (u & 0x80000000u) ? (u ^ 0x80000000u) : ~u;
    }
}

extern "C" void kernel_launch(void* const* d_in, const int* in_sizes, int n_in,
                              void* d_out, int out_size, void* d_ws, size_t ws_size,
                              hipStream_t stream) {
    const float* x  = (const float*)d_in[0];
    const float* w1 = (const float*)d_in[1];
    const float* b1 = (const float*)d_in[2];
    const float* w2 = (const float*)d_in[3];
    const float* b2 = (const float*)d_in[4];

    uint4*    Bpf  = (uint4*)d_ws;                  // 2 MB fragment-major bf16
    unsigned* outu = (unsigned*)d_out;

    pack_w<<<dim3(512), dim3(256), 0, stream>>>(w1, w2, Bpf, outu);

    const int nblk = 62 * 4;                        // 248, batch-aligned
    gemm_max<<<dim3(nblk), dim3(1024), 0, stream>>>(x, (const uint4*)Bpf, b1, b2, outu);

    unmap_out<<<dim3(2), dim3(256), 0, stream>>>(outu);
}

// Round 11
// 75.537 us; speedup vs baseline: 1.2371x; 1.2371x over previous
//
#include <hip/hip_runtime.h>

// ---------------------------------------------------------------------------
// MalConvLowMem as GEMM: M=15748 windows (4096 contiguous floats), N=256
// (w1|w2), K=4096; epilogue g=(c1+b1)*sigmoid(c2+b2), max over positions.
// R11 = R9 schedule + wave tile 32x32 with 16x16 MFMA (acc[2][2], 4 indep
// chains). 16 waves = 2 row-groups x 8 col-groups; A-LDS read traffic halves
// vs R9 (64KB/step/CU), bank pattern stays 2-way-free. Col-group g owns
// {g*16..+15} (c1, nf=0) u {128+g*16..+15} (c2, nf=1): gate pair in SAME
// lane, different acc register -> shuffle-free pairing in epilogue.
// A in LDS ring-4 (8KB/slot), per-step lgkmcnt(0)+s_barrier; B in regs,
// fragment-major; grid 248 batch-aligned.
// ---------------------------------------------------------------------------

#define T_LEN 2000000
#define P_CNT 3937
#define M_TOT 15748
#define KD    4096

typedef __attribute__((ext_vector_type(8))) short short8;
typedef __attribute__((ext_vector_type(4))) float f32x4;

static __device__ __forceinline__ unsigned short f2bf(float f) {
    unsigned u = __builtin_bit_cast(unsigned, f);
    unsigned r = (u + 0x7FFFu + ((u >> 16) & 1u)) >> 16;   // RNE
    return (unsigned short)r;
}

static __device__ __forceinline__ unsigned ordenc(float f) {
    unsigned u = __builtin_bit_cast(unsigned, f);
    return (u & 0x80000000u) ? ~u : (u | 0x80000000u);
}

// (batch bb, position p<=3936) -> flat float offset of window start in x
static __device__ __forceinline__ size_t row_base_bp(int bb, int p) {
    int j, kp;
    if (p < 3875) { j = p / 125; kp = p - j * 125; }
    else          { j = 31;      kp = p - 3875; }
    long pos = (long)j * 63489 + (long)kp * 512;
    return ((size_t)bb * T_LEN + (size_t)pos) * 8u;
}

// 4 fp32 -> 4 bf16 (uint2) via v_cvt_pk_bf16_f32 (RNE)
static __device__ __forceinline__ uint2 cvt4(float4 v) {
    unsigned lo, hi;
    asm("v_cvt_pk_bf16_f32 %0, %1, %2" : "=v"(lo) : "v"(v.x), "v"(v.y));
    asm("v_cvt_pk_bf16_f32 %0, %1, %2" : "=v"(hi) : "v"(v.z), "v"(v.w));
    uint2 u; u.x = lo; u.y = hi;
    return u;
}

// ---------------------------------------------------------------------------
// Kernel 1: repack weights fragment-major (16x16 MFMA) with per-col-group
// gate pairing. uint4 chunk c = (((ks*2+kq)*2+nf)*8+g)*64 + l holds:
//   n = nf==0 ? g*16+(l&15) : 128+g*16+(l&15)
//   k = ks*64 + kq*32 + (l>>4)*8 + 0..7
//   W'[n][k] = (n<128?w1:w2)[n&127][e=k&7][t=k>>3] as bf16.
// Also init 512 output slots to order-encoded -inf.
// ---------------------------------------------------------------------------
__global__ __launch_bounds__(256) void pack_w(const float* __restrict__ w1,
                                              const float* __restrict__ w2,
                                              uint4* __restrict__ Bpf,
                                              unsigned* __restrict__ outu) {
    int c = blockIdx.x * 256 + threadIdx.x;         // grid 512 -> 131072
    if (c < 512) outu[c] = 0u;
    if (c >= 131072) return;
    int l  = c & 63;
    int g  = (c >> 6) & 7;
    int nf = (c >> 9) & 1;
    int kq = (c >> 10) & 1;
    int ks = c >> 11;
    int n  = nf ? (128 + g * 16 + (l & 15)) : (g * 16 + (l & 15));
    int kb = ks * 64 + kq * 32 + ((l >> 4) << 3);
    const float* src = (n < 128) ? w1 : w2;
    int cc = n & 127;
    unsigned short h[8];
#pragma unroll
    for (int j = 0; j < 8; ++j) {
        int k = kb + j;
        h[j] = f2bf(src[cc * 4096 + (k & 7) * 512 + (k >> 3)]);
    }
    uint4 v;
    v.x = (unsigned)h[0] | ((unsigned)h[1] << 16);
    v.y = (unsigned)h[2] | ((unsigned)h[3] << 16);
    v.z = (unsigned)h[4] | ((unsigned)h[5] << 16);
    v.w = (unsigned)h[6] | ((unsigned)h[7] << 16);
    Bpf[c] = v;
}

// ---------------------------------------------------------------------------
// Kernel 2: GEMM + gate + max. 1024 thr / 16 waves; wave (mg=w>>3, g=w&7)
// owns rows mg*32..+31 and col-group g (32 virtual cols). acc[2][2] f32x4.
// ---------------------------------------------------------------------------
#define LOAD_B(BB, KS)                                                         \
    do {                                                                       \
        _Pragma("unroll")                                                      \
        for (int kq = 0; kq < 2; ++kq)                                         \
            _Pragma("unroll")                                                  \
            for (int nf = 0; nf < 2; ++nf)                                     \
                BB[kq][nf] = Bq[((KS) * 4 + kq * 2 + nf) * 512 + bbase];       \
    } while (0)

#define STEP(KS, BCUR, BNXT)                                                   \
    do {                                                                       \
        const int ks_ = (KS);                                                  \
        const int ksn = (ks_ + 1 < 64) ? ks_ + 1 : 63;                         \
        LOAD_B(BNXT, ksn);                                                     \
        const int ksl = (ks_ + 4 < 64) ? ks_ + 4 : 63;                         \
        float4 aF = *(const float4*)(x + aoff + (size_t)(ksl * 64));           \
        const char* As = smem + (ks_ & 3) * 8192;                              \
        _Pragma("unroll")                                                      \
        for (int kq = 0; kq < 2; ++kq) {                                       \
            short8 af0 = *(const short8*)(As + aro[kq][0]);                    \
            short8 af1 = *(const short8*)(As + aro[kq][1]);                    \
            short8 b0  = __builtin_bit_cast(short8, BCUR[kq][0]);              \
            short8 b1  = __builtin_bit_cast(short8, BCUR[kq][1]);              \
            acc[0][0] = __builtin_amdgcn_mfma_f32_16x16x32_bf16(               \
                af0, b0, acc[0][0], 0, 0, 0);                                  \
            acc[1][0] = __builtin_amdgcn_mfma_f32_16x16x32_bf16(               \
                af1, b0, acc[1][0], 0, 0, 0);                                  \
            acc[0][1] = __builtin_amdgcn_mfma_f32_16x16x32_bf16(               \
                af0, b1, acc[0][1], 0, 0, 0);                                  \
            acc[1][1] = __builtin_amdgcn_mfma_f32_16x16x32_bf16(               \
                af1, b1, acc[1][1], 0, 0, 0);                                  \
        }                                                                      \
        *(uint2*)(smem + ((ks_ + 2) & 3) * 8192 + awb) = cvt4(aA);             \
        aA = aB; aB = aF;                                                      \
        asm volatile("s_waitcnt lgkmcnt(0)" ::: "memory");                     \
        __builtin_amdgcn_s_barrier();                                          \
        asm volatile("" ::: "memory");                                         \
    } while (0)

__global__ __launch_bounds__(1024, 4) void gemm_max(const float* __restrict__ x,
                                                    const uint4* __restrict__ Bq,
                                                    const float* __restrict__ b1,
                                                    const float* __restrict__ b2,
                                                    unsigned* __restrict__ outu) {
    __shared__ __align__(16) char smem[32768];      // ring-4 of 8KB

    const int t    = threadIdx.x;
    const int lane = t & 63;
    const int w    = t >> 6;                        // wave 0..15
    const int g    = w & 7;                         // col-group
    const int mg   = w >> 3;                        // row-group
    const int bid  = blockIdx.x;
    const int bb   = bid / 62;                      // batch (block-uniform)
    const int p0   = (bid % 62) * 64;               // first position of block

    // ---- A staging: thread t handles row=t>>4 (0..63), k-chunk t&15 ----
    const int rowS = t >> 4;
    const int kcS  = t & 15;
    int pS = p0 + rowS; if (pS > P_CNT - 1) pS = P_CNT - 1;
    const size_t aoff = row_base_bp(bb, pS) + (size_t)(kcS * 4);
    const int    awb  = (rowS * 128 + kcS * 8) ^ ((rowS & 7) << 4);

    // ---- A fragment read offsets [kq][mf] (XOR-swizzled, 2-way-free):
    // row = mg*32 + mf*16 + (lane&15) ----
    int aro[2][2];
#pragma unroll
    for (int kq = 0; kq < 2; ++kq)
#pragma unroll
        for (int mf = 0; mf < 2; ++mf) {
            int row = mg * 32 + mf * 16 + (lane & 15);
            aro[kq][mf] = (row * 128 + kq * 64 + (lane >> 4) * 16)
                          ^ ((row & 7) << 4);
        }

    const int bbase = g * 64 + lane;                // uint4 units

    // ---- prologue: stage tiles 0,1; prime pipelines ----
#pragma unroll
    for (int pt = 0; pt < 2; ++pt) {
        float4 v = *(const float4*)(x + aoff + pt * 64);
        *(uint2*)(smem + pt * 8192 + awb) = cvt4(v);
    }
    __syncthreads();

    float4 aA = *(const float4*)(x + aoff + 128);   // tile 2
    float4 aB = *(const float4*)(x + aoff + 192);   // tile 3
    uint4 BX[2][2], BY[2][2];
    LOAD_B(BX, 0);

    f32x4 acc[2][2];
#pragma unroll
    for (int mf = 0; mf < 2; ++mf)
#pragma unroll
        for (int nf = 0; nf < 2; ++nf) acc[mf][nf] = (f32x4){0.f, 0.f, 0.f, 0.f};

    for (int ks = 0; ks < 64; ks += 2) {
        STEP(ks, BX, BY);
        STEP(ks + 1, BY, BX);
    }

    // ---- epilogue: gate pair is same-lane (acc[.][0]=c1, acc[.][1]=c2) ----
    const int   cidx = g * 16 + (lane & 15);
    const float bb1  = b1[cidx];
    const float bb2  = b2[cidx];
    float best = -3.4e38f;
#pragma unroll
    for (int mf = 0; mf < 2; ++mf)
#pragma unroll
        for (int q = 0; q < 4; ++q) {
            float c1 = acc[mf][0][q] + bb1;
            float c2 = acc[mf][1][q] + bb2;
            float gv = c1 / (1.f + __expf(-c2));
            best = fmaxf(best, gv);
        }
    // reduce over row-slots (lane bits 4,5); batch is block-uniform
    best = fmaxf(best, __shfl_xor(best, 16));
    best = fmaxf(best, __shfl_xor(best, 32));
    if (lane < 16)
        atomicMax(&outu[bb * 128 + cidx], ordenc(best));
}

// ---------------------------------------------------------------------------
// Kernel 3: decode order-encoded uints to floats in place.
// ---------------------------------------------------------------------------
__global__ __launch_bounds__(256) void unmap_out(unsigned* __restrict__ outu) {
    int i = blockIdx.x * 256 + threadIdx.x;
    if (i < 512) {
        unsigned u = outu[i];
        outu[i] = (u & 0x80000000u) ? (u ^ 0x80000000u) : ~u;
    }
}

extern "C" void kernel_launch(void* const* d_in, const int* in_sizes, int n_in,
                              void* d_out, int out_size, void* d_ws, size_t ws_size,
                              hipStream_t stream) {
    const float* x  = (const float*)d_in[0];
    const float* w1 = (const float*)d_in[1];
    const float* b1 = (const float*)d_in[2];
    const float* w2 = (const float*)d_in[3];
    const float* b2 = (const float*)d_in[4];

    uint4*    Bpf  = (uint4*)d_ws;                  // 2 MB fragment-major bf16
    unsigned* outu = (unsigned*)d_out;

    pack_w<<<dim3(512), dim3(256), 0, stream>>>(w1, w2, Bpf, outu);

    const int nblk = 62 * 4;                        // 248, batch-aligned
    gemm_max<<<dim3(nblk), dim3(1024), 0, stream>>>(x, (const uint4*)Bpf, b1, b2, outu);

    unmap_out<<<dim3(2), dim3(256), 0, stream>>>(outu);
}

// Round 12
// 70.156 us; speedup vs baseline: 1.3320x; 1.0767x over previous
//
#include <hip/hip_runtime.h>

// ---------------------------------------------------------------------------
// MalConvLowMem as GEMM: M=15748 windows (4096 contiguous floats), N=256
// (w1|w2), K=4096; epilogue g=(c1+b1)*sigmoid(c2+b2), max over positions.
// R12 = R9 data paths + superstep sync: A in LDS ring-8 (8KB/slot, 64KB),
// ONE lgkmcnt(15)+s_barrier per 2 K-steps (32 barriers total, no full LDS
// drain ever). Write slot (s+4)&7 at step s -> 2 barriers before read;
// counted lgkmcnt(15) + in-order DS completion guarantees publish.
// B in regs (fragment-major, per-wave-private 16-col gate-paired slices),
// 16 waves (1024 thr), wave tile 64x16, acc[4] chains; grid 248 batch-aligned.
// ---------------------------------------------------------------------------

#define T_LEN 2000000
#define P_CNT 3937
#define M_TOT 15748
#define KD    4096

typedef __attribute__((ext_vector_type(8))) short short8;
typedef __attribute__((ext_vector_type(4))) float f32x4;

static __device__ __forceinline__ unsigned short f2bf(float f) {
    unsigned u = __builtin_bit_cast(unsigned, f);
    unsigned r = (u + 0x7FFFu + ((u >> 16) & 1u)) >> 16;   // RNE
    return (unsigned short)r;
}

static __device__ __forceinline__ unsigned ordenc(float f) {
    unsigned u = __builtin_bit_cast(unsigned, f);
    return (u & 0x80000000u) ? ~u : (u | 0x80000000u);
}

// (batch bb, position p<=3936) -> flat float offset of window start in x
static __device__ __forceinline__ size_t row_base_bp(int bb, int p) {
    int j, kp;
    if (p < 3875) { j = p / 125; kp = p - j * 125; }
    else          { j = 31;      kp = p - 3875; }
    long pos = (long)j * 63489 + (long)kp * 512;
    return ((size_t)bb * T_LEN + (size_t)pos) * 8u;
}

// 4 fp32 -> 4 bf16 (uint2) via v_cvt_pk_bf16_f32 (RNE)
static __device__ __forceinline__ uint2 cvt4(float4 v) {
    unsigned lo, hi;
    asm("v_cvt_pk_bf16_f32 %0, %1, %2" : "=v"(lo) : "v"(v.x), "v"(v.y));
    asm("v_cvt_pk_bf16_f32 %0, %1, %2" : "=v"(hi) : "v"(v.z), "v"(v.w));
    uint2 u; u.x = lo; u.y = hi;
    return u;
}

// ---------------------------------------------------------------------------
// Kernel 1 (unchanged from R9, proven): repack weights fragment-major with
// gate-pair col permutation. uint4 chunk c = ((ks*2+kq)*16 + w)*64 + l:
//   cl=l&15; n = cl<8 ? w*8+cl : 128+w*8+(cl-8); k = ks*64+kq*32+(l>>4)*8+0..7
//   W'[n][k] = (n<128?w1:w2)[n&127][e=k&7][t=k>>3] as bf16. Init outu.
// ---------------------------------------------------------------------------
__global__ __launch_bounds__(256) void pack_w(const float* __restrict__ w1,
                                              const float* __restrict__ w2,
                                              uint4* __restrict__ Bpf,
                                              unsigned* __restrict__ outu) {
    int c = blockIdx.x * 256 + threadIdx.x;         // grid 512 -> 131072
    if (c < 512) outu[c] = 0u;
    if (c >= 131072) return;
    int l  = c & 63;
    int w  = (c >> 6) & 15;                          // wave 0..15
    int kq = (c >> 10) & 1;
    int ks = c >> 11;
    int cl = l & 15;
    int n  = (cl < 8) ? (w * 8 + cl) : (128 + w * 8 + (cl - 8));
    int kb = ks * 64 + kq * 32 + ((l >> 4) << 3);
    const float* src = (n < 128) ? w1 : w2;
    int cc = n & 127;
    unsigned short h[8];
#pragma unroll
    for (int j = 0; j < 8; ++j) {
        int k = kb + j;
        h[j] = f2bf(src[cc * 4096 + (k & 7) * 512 + (k >> 3)]);
    }
    uint4 v;
    v.x = (unsigned)h[0] | ((unsigned)h[1] << 16);
    v.y = (unsigned)h[2] | ((unsigned)h[3] << 16);
    v.z = (unsigned)h[4] | ((unsigned)h[5] << 16);
    v.w = (unsigned)h[6] | ((unsigned)h[7] << 16);
    Bpf[c] = v;
}

// ---------------------------------------------------------------------------
// Kernel 2: GEMM + gate + max. 1024 thr / 16 waves, wave tile 64 rows x
// 16 cols (gate-paired), acc[4] f32x4. A ring-8 in LDS (8 x 8KB).
// Superstep = 2 K-tiles, one lgkmcnt(15)+s_barrier at the end.
// ---------------------------------------------------------------------------
#define LOAD_B(BB, KS)                                                         \
    do {                                                                       \
        _Pragma("unroll")                                                      \
        for (int kq = 0; kq < 2; ++kq)                                         \
            BB[kq] = Bq[((KS) * 2 + kq) * 1024 + bbase];                       \
    } while (0)

// One K-tile, NO barrier. Loads A for tile KS+6, writes tile KS+4's slot.
#define STEP_NB(KS, BCUR, BNXT)                                                \
    do {                                                                       \
        const int ks_ = (KS);                                                  \
        const int ksn = (ks_ + 1 < 64) ? ks_ + 1 : 63;                         \
        LOAD_B(BNXT, ksn);                                                     \
        const int ksl = (ks_ + 6 < 64) ? ks_ + 6 : 63;                         \
        float4 aF = *(const float4*)(x + aoff + (size_t)(ksl * 64));           \
        const char* As = smem + (ks_ & 7) * 8192;                              \
        _Pragma("unroll")                                                      \
        for (int kq = 0; kq < 2; ++kq) {                                       \
            short8 b = __builtin_bit_cast(short8, BCUR[kq]);                   \
            _Pragma("unroll")                                                  \
            for (int mf = 0; mf < 4; ++mf) {                                   \
                short8 af = *(const short8*)(As + aro[kq][mf]);                \
                acc[mf] = __builtin_amdgcn_mfma_f32_16x16x32_bf16(             \
                    af, b, acc[mf], 0, 0, 0);                                  \
            }                                                                  \
        }                                                                      \
        if (ks_ + 4 < 64)                                                      \
            *(uint2*)(smem + ((ks_ + 4) & 7) * 8192 + awb) = cvt4(aA);         \
        aA = aB; aB = aF;                                                      \
    } while (0)

__global__ __launch_bounds__(1024, 4) void gemm_max(const float* __restrict__ x,
                                                    const uint4* __restrict__ Bq,
                                                    const float* __restrict__ b1,
                                                    const float* __restrict__ b2,
                                                    unsigned* __restrict__ outu) {
    __shared__ __align__(16) char smem[65536];      // ring-8 of 8KB

    const int t    = threadIdx.x;
    const int lane = t & 63;
    const int w    = t >> 6;                        // wave 0..15
    const int bid  = blockIdx.x;
    const int bb   = bid / 62;                      // batch (block-uniform)
    const int p0   = (bid % 62) * 64;               // first position of block

    // ---- A staging: thread t handles row=t>>4 (0..63), k-chunk t&15 ----
    const int rowS = t >> 4;
    const int kcS  = t & 15;
    int pS = p0 + rowS; if (pS > P_CNT - 1) pS = P_CNT - 1;
    const size_t aoff = row_base_bp(bb, pS) + (size_t)(kcS * 4);
    const int    awb  = (rowS * 128 + kcS * 8) ^ ((rowS & 7) << 4);

    // ---- A fragment read offsets [kq][mf] (XOR-swizzled, 2-way-free) ----
    int aro[2][4];
#pragma unroll
    for (int kq = 0; kq < 2; ++kq)
#pragma unroll
        for (int mf = 0; mf < 4; ++mf) {
            int row = mf * 16 + (lane & 15);
            aro[kq][mf] = (row * 128 + kq * 64 + (lane >> 4) * 16)
                          ^ ((row & 7) << 4);
        }

    const int bbase = w * 64 + lane;                // uint4 units

    // ---- prologue: stage tiles 0..3; prime pipelines ----
#pragma unroll
    for (int pt = 0; pt < 4; ++pt) {
        float4 v = *(const float4*)(x + aoff + pt * 64);
        *(uint2*)(smem + pt * 8192 + awb) = cvt4(v);
    }
    __syncthreads();

    float4 aA = *(const float4*)(x + aoff + 256);   // tile 4
    float4 aB = *(const float4*)(x + aoff + 320);   // tile 5
    uint4 BX[2], BY[2];
    LOAD_B(BX, 0);

    f32x4 acc[4];
#pragma unroll
    for (int mf = 0; mf < 4; ++mf) acc[mf] = (f32x4){0.f, 0.f, 0.f, 0.f};

    // ---- main loop: 32 supersteps of 2 K-tiles, ONE counted barrier each.
    // Publish proof: write(slot s+4) at step s has >=18 newer DS ops by the
    // barrier at end of step s+3 (odd); lgkmcnt(15) + in-order DS => done
    // before any wave reads it at step s+4. Intra-superstep: writes hit
    // slots s+4/s+5, reads s/s+1 -- disjoint mod 8.
    for (int ks = 0; ks < 64; ks += 2) {
        STEP_NB(ks, BX, BY);
        STEP_NB(ks + 1, BY, BX);
        asm volatile("s_waitcnt lgkmcnt(15)" ::: "memory");
        __builtin_amdgcn_s_barrier();
        asm volatile("" ::: "memory");
    }

    // ---- epilogue: in-register gate + max (no LDS) ----
    // lane cl=lane&15: cl<8 -> col c1 = w*8+cl; partner c2 in lane^8.
    const int   cidx = w * 8 + (lane & 7);
    const float bb1  = b1[cidx];
    const float bb2  = b2[cidx];
    float best = -3.4e38f;
#pragma unroll
    for (int mf = 0; mf < 4; ++mf)
#pragma unroll
        for (int q = 0; q < 4; ++q) {
            float v  = acc[mf][q];
            float ov = __shfl_xor(v, 8);
            float c1 = v + bb1;
            float c2 = ov + bb2;
            float g  = c1 / (1.f + __expf(-c2));
            best = fmaxf(best, g);
        }
    best = fmaxf(best, __shfl_xor(best, 16));
    best = fmaxf(best, __shfl_xor(best, 32));
    if (lane < 8)
        atomicMax(&outu[bb * 128 + w * 8 + lane], ordenc(best));
}

// ---------------------------------------------------------------------------
// Kernel 3: decode order-encoded uints to floats in place.
// ---------------------------------------------------------------------------
__global__ __launch_bounds__(256) void unmap_out(unsigned* __restrict__ outu) {
    int i = blockIdx.x * 256 + threadIdx.x;
    if (i < 512) {
        unsigned u = outu[i];
        outu[i] = (u & 0x80000000u) ? (u ^ 0x80000000u) : ~u;
    }
}

extern "C" void kernel_launch(void* const* d_in, const int* in_sizes, int n_in,
                              void* d_out, int out_size, void* d_ws, size_t ws_size,
                              hipStream_t stream) {
    const float* x  = (const float*)d_in[0];
    const float* w1 = (const float*)d_in[1];
    const float* b1 = (const float*)d_in[2];
    const float* w2 = (const float*)d_in[3];
    const float* b2 = (const float*)d_in[4];

    uint4*    Bpf  = (uint4*)d_ws;                  // 2 MB fragment-major bf16
    unsigned* outu = (unsigned*)d_out;

    pack_w<<<dim3(512), dim3(256), 0, stream>>>(w1, w2, Bpf, outu);

    const int nblk = 62 * 4;                        // 248, batch-aligned
    gemm_max<<<dim3(nblk), dim3(1024), 0, stream>>>(x, (const uint4*)Bpf, b1, b2, outu);

    unmap_out<<<dim3(2), dim3(256), 0, stream>>>(outu);
}